// Round 1
// baseline (29.411 us; speedup 1.0000x reference)
//
#include <hip/hip_runtime.h>

// DWA_CNN: B=32, T=2048, C=128, K=3, F=8, P=2046
// out[b,p,f] = relu(bias[f] + DTW-path-sum of dots), where
//   dots[i][j] = <x[b,p+i,:], w[j,:,f]>  (C=128)
// Strategy: per block, precompute G[t][k][f] = <x[b,t,:], w[k,:,f]> and row
// norms into LDS (phase 1), then run the exact reference DTW + backtrace per
// (p,f) output (phase 2). All DP state in constant-indexed registers.

#define TT   126          // positions per block
#define ROWS 128          // G rows per block = TT + K - 1 = 128
#define GSTRIDE 29        // LDS row stride (floats); gcd(29,32)=1 -> conflict-free
#define BIGV 1234567891011.0f

// Backtrace step for compile-time state (I,J), exact jnp.argmin tie semantics
// (first index of minimum). cands = [cost[I-1][J-1], cost[I][J-1], cost[I-1][J]].
#define TRACE_CASE(I, J)                                                      \
  case (((I) << 2) | (J)): {                                                  \
    const float ca = cost[(I)-1][(J)-1];                                      \
    const float cb = cost[(I)][(J)-1];                                        \
    const float cc = cost[(I)-1][(J)];                                        \
    const int m = (ca <= cb) ? ((ca <= cc) ? 0 : 2) : ((cb <= cc) ? 1 : 2);   \
    const int i2 = (I) - ((m == 1) ? 0 : 1);                                  \
    const int j2 = (J) - ((m == 2) ? 0 : 1);                                  \
    const bool nxt = (i2 > 0) && (j2 > 0);                                    \
    if (nxt) {                                                                \
      const float add =                                                       \
          (m == 0) ? dots[((I) >= 2) ? (I)-2 : 0][((J) >= 2) ? (J)-2 : 0]     \
        : (m == 1) ? dots[(I)-1][((J) >= 2) ? (J)-2 : 0]                      \
                   : dots[((I) >= 2) ? (I)-2 : 0][(J)-1];                     \
      acc += add;                                                             \
    }                                                                         \
    st = (i2 << 2) | j2;                                                      \
    active = nxt;                                                             \
  } break;

__global__ __launch_bounds__(128) void dwa_cnn_kernel(
    const float* __restrict__ x, const float* __restrict__ w,
    const float* __restrict__ bias, float* __restrict__ out)
{
  constexpr int T = 2048, C = 128, P = 2046;

  __shared__ float G[ROWS][GSTRIDE];  // [row][0..23]=G(k,f), [24]=|x row|^2
  __shared__ float WN[24];            // |w[k,:,f]|^2, idx = k*8+f
  __shared__ float BI[8];

  const int b  = blockIdx.y;
  const int p0 = blockIdx.x * TT;
  const int tid = threadIdx.x;

  // phase 0: filter norms + bias (tiny, L2-resident)
  if (tid < 24) {
    const int k = tid >> 3, f = tid & 7;
    float s = 0.f;
    for (int c = 0; c < C; ++c) {
      const float v = w[(k * C + c) * 8 + f];
      s = fmaf(v, v, s);
    }
    WN[tid] = s;
  }
  if (tid < 8) BI[tid] = bias[tid];

  // phase 1: one t-row per thread -> 24 dot products + norm
  {
    const int t = p0 + tid;
    if (t < T) {
      const float* xr = x + ((size_t)b * T + t) * C;
      float acc[24];
      #pragma unroll
      for (int q = 0; q < 24; ++q) acc[q] = 0.f;
      float nrm = 0.f;
      #pragma unroll 2
      for (int c4 = 0; c4 < C; c4 += 4) {
        const float4 xv = *(const float4*)(xr + c4);
        const float xsv[4] = {xv.x, xv.y, xv.z, xv.w};
        #pragma unroll
        for (int j = 0; j < 4; ++j) {
          const float xs = xsv[j];
          nrm = fmaf(xs, xs, nrm);
          #pragma unroll
          for (int k = 0; k < 3; ++k) {
            #pragma unroll
            for (int f = 0; f < 8; ++f) {
              // wave-uniform address -> scalar (SMEM) loads, off the LDS/VMEM pipes
              acc[k * 8 + f] = fmaf(xs, w[((k * C + c4 + j) * 8) + f], acc[k * 8 + f]);
            }
          }
        }
      }
      #pragma unroll
      for (int q = 0; q < 24; ++q) G[tid][q] = acc[q];
      G[tid][24] = nrm;
    }
  }
  __syncthreads();

  // phase 2: one (p, f) output per thread-iteration
  for (int o = tid; o < TT * 8; o += 128) {
    const int pl = o >> 3, f = o & 7;
    const int p  = p0 + pl;
    if (p >= P) break;  // o monotone -> once out of range, all later are too

    float xn[3], dots[3][3];
    #pragma unroll
    for (int i = 0; i < 3; ++i) {
      xn[i] = G[pl + i][24];
      #pragma unroll
      for (int j = 0; j < 3; ++j) dots[i][j] = G[pl + i][j * 8 + f];
    }

    float D[3][3];
    #pragma unroll
    for (int i = 0; i < 3; ++i) {
      #pragma unroll
      for (int j = 0; j < 3; ++j) {
        const float sq = xn[i] + WN[j * 8 + f] - 2.f * dots[i][j];
        D[i][j] = sqrtf(fmaxf(sq, 0.f));
      }
    }

    // forward DTW cost (4x4), constant-indexed -> registers
    float cost[4][4];
    cost[0][0] = 0.f;  cost[0][1] = BIGV; cost[0][2] = BIGV; cost[0][3] = BIGV;
    #pragma unroll
    for (int i = 1; i <= 3; ++i) {
      cost[i][0] = BIGV;
      #pragma unroll
      for (int j = 1; j <= 3; ++j) {
        cost[i][j] = D[i-1][j-1] +
            fminf(fminf(cost[i][j-1], cost[i-1][j-1]), cost[i-1][j]);
      }
    }

    // backtrace: start (3,3), acc = dots[2][2], 2K-1 = 5 steps
    float acc = dots[2][2];
    int st = (3 << 2) | 3;
    bool active = true;
    #pragma unroll 1
    for (int s = 0; s < 5; ++s) {
      if (!active) break;
      switch (st) {
        TRACE_CASE(1, 1)
        TRACE_CASE(1, 2)
        TRACE_CASE(1, 3)
        TRACE_CASE(2, 1)
        TRACE_CASE(2, 2)
        TRACE_CASE(2, 3)
        TRACE_CASE(3, 1)
        TRACE_CASE(3, 2)
        TRACE_CASE(3, 3)
        default: active = false; break;
      }
    }

    out[((size_t)b * P + p) * 8 + f] = fmaxf(acc + BI[f], 0.f);
  }
}

extern "C" void kernel_launch(void* const* d_in, const int* in_sizes, int n_in,
                              void* d_out, int out_size, void* d_ws, size_t ws_size,
                              hipStream_t stream) {
  const float* x    = (const float*)d_in[0];
  const float* w    = (const float*)d_in[1];
  const float* bias = (const float*)d_in[2];
  float* out        = (float*)d_out;

  constexpr int P = 2046, B = 32;
  dim3 grid((P + TT - 1) / TT, B);  // 17 x 32 = 544 blocks
  dwa_cnn_kernel<<<grid, 128, 0, stream>>>(x, w, bias, out);
}

// Round 2
// 28.654 us; speedup vs baseline: 1.0264x; 1.0264x over previous
//
#include <hip/hip_runtime.h>

// DWA_CNN: B=32, T=2048, C=128, K=3, F=8, P=2046
// out[b,p,f] = relu(bias[f] + DTW-path-sum of dots), where
//   dots[i][j] = <x[b,p+i,:], w[j,:,f]>  (C=128)
//
// v2: w staged in LDS (broadcast ds_read_b128, no per-lane VMEM for w);
//     TT=62/ROWS=64 tiles, 128 threads = 2 waves with C split across waves
//     (wave0 c<64, wave1 c>=64, combined via LDS partials).
//     Grid 33x32=1056 blocks, all co-resident, ~2 waves/SIMD.

#define TT   62           // positions per block (2046 = 33 * 62 exactly)
#define ROWS 64           // G rows per block = TT + K - 1
#define GSTRIDE 29        // LDS row stride (floats); gcd(29,32)=1
#define PSTRIDE 26
#define BIGV 1234567891011.0f

// Backtrace step for compile-time state (I,J), exact jnp.argmin tie semantics
// (first index of minimum). cands = [cost[I-1][J-1], cost[I][J-1], cost[I-1][J]].
#define TRACE_CASE(I, J)                                                      \
  case (((I) << 2) | (J)): {                                                  \
    const float ca = cost[(I)-1][(J)-1];                                      \
    const float cb = cost[(I)][(J)-1];                                        \
    const float cc = cost[(I)-1][(J)];                                        \
    const int m = (ca <= cb) ? ((ca <= cc) ? 0 : 2) : ((cb <= cc) ? 1 : 2);   \
    const int i2 = (I) - ((m == 1) ? 0 : 1);                                  \
    const int j2 = (J) - ((m == 2) ? 0 : 1);                                  \
    const bool nxt = (i2 > 0) && (j2 > 0);                                    \
    if (nxt) {                                                                \
      const float add =                                                       \
          (m == 0) ? dots[((I) >= 2) ? (I)-2 : 0][((J) >= 2) ? (J)-2 : 0]     \
        : (m == 1) ? dots[(I)-1][((J) >= 2) ? (J)-2 : 0]                      \
                   : dots[((I) >= 2) ? (I)-2 : 0][(J)-1];                     \
      acc += add;                                                             \
    }                                                                         \
    st = (i2 << 2) | j2;                                                      \
    active = nxt;                                                             \
  } break;

__global__ __launch_bounds__(128) void dwa_cnn_kernel(
    const float* __restrict__ x, const float* __restrict__ w,
    const float* __restrict__ bias, float* __restrict__ out)
{
  constexpr int T = 2048, C = 128, P = 2046;

  __shared__ float W2[3072];            // [c][q], q = k*8+f, stride 24
  __shared__ float G[ROWS][GSTRIDE];    // [row][0..23]=dots, [24]=|x row|^2
  __shared__ float Pt[ROWS][PSTRIDE];   // wave-1 partials
  __shared__ float WN[24];              // |w[k,:,f]|^2
  __shared__ float BI[8];

  const int b   = blockIdx.y;
  const int p0  = blockIdx.x * TT;
  const int tid = threadIdx.x;

  // ---- stage w into LDS: W2[c*24 + k*8 + f] = w[(k*128+c)*8+f] ----
  for (int i = tid; i < 3072; i += 128) {
    const int k = i >> 10, c = (i >> 3) & 127, f = i & 7;
    W2[c * 24 + k * 8 + f] = w[i];
  }
  if (tid < 8) BI[tid] = bias[tid];
  __syncthreads();

  // ---- phase 1: thread = (row r, c-half ch); ch uniform per wave ----
  const int ch = tid >> 6;     // wave 0 -> c in [0,64), wave 1 -> [64,128)
  const int r  = tid & 63;

  float acc[25];               // [0..23] partial dots, [24] partial |x|^2
  #pragma unroll
  for (int q = 0; q < 25; ++q) acc[q] = 0.f;

  {
    const float* xr = x + ((size_t)b * T + p0 + r) * C + ch * 64;
    const float* wl = &W2[ch * 64 * 24];
    #pragma unroll 4
    for (int c4 = 0; c4 < 64; c4 += 4) {
      const float4 xv = *(const float4*)(xr + c4);
      const float xsv[4] = {xv.x, xv.y, xv.z, xv.w};
      #pragma unroll
      for (int j = 0; j < 4; ++j) {
        const float xs = xsv[j];
        acc[24] = fmaf(xs, xs, acc[24]);
        const float4* wr = (const float4*)&wl[(c4 + j) * 24];  // 96B aligned
        #pragma unroll
        for (int v = 0; v < 6; ++v) {
          const float4 wv = wr[v];   // wave-uniform address -> LDS broadcast
          acc[v * 4 + 0] = fmaf(xs, wv.x, acc[v * 4 + 0]);
          acc[v * 4 + 1] = fmaf(xs, wv.y, acc[v * 4 + 1]);
          acc[v * 4 + 2] = fmaf(xs, wv.z, acc[v * 4 + 2]);
          acc[v * 4 + 3] = fmaf(xs, wv.w, acc[v * 4 + 3]);
        }
      }
    }
  }

  if (ch == 1) {
    #pragma unroll
    for (int q = 0; q < 25; ++q) Pt[r][q] = acc[q];
  }
  __syncthreads();

  if (ch == 0) {
    #pragma unroll
    for (int q = 0; q < 25; ++q) G[r][q] = acc[q] + Pt[r][q];
  } else if (r < 24) {
    // wave 1: filter norms from staged w (full C)
    float s = 0.f;
    for (int c = 0; c < C; ++c) {
      const float v = W2[c * 24 + r];
      s = fmaf(v, v, s);
    }
    WN[r] = s;
  }
  __syncthreads();

  // ---- phase 2: one (p, f) output per thread-iteration ----
  for (int o = tid; o < TT * 8; o += 128) {
    const int pl = o >> 3, f = o & 7;
    const int p  = p0 + pl;

    float xn[3], dots[3][3];
    #pragma unroll
    for (int i = 0; i < 3; ++i) {
      xn[i] = G[pl + i][24];
      #pragma unroll
      for (int j = 0; j < 3; ++j) dots[i][j] = G[pl + i][j * 8 + f];
    }

    float D[3][3];
    #pragma unroll
    for (int i = 0; i < 3; ++i) {
      #pragma unroll
      for (int j = 0; j < 3; ++j) {
        const float sq = xn[i] + WN[j * 8 + f] - 2.f * dots[i][j];
        D[i][j] = sqrtf(fmaxf(sq, 0.f));
      }
    }

    // forward DTW cost (4x4), constant-indexed -> registers
    float cost[4][4];
    cost[0][0] = 0.f;  cost[0][1] = BIGV; cost[0][2] = BIGV; cost[0][3] = BIGV;
    #pragma unroll
    for (int i = 1; i <= 3; ++i) {
      cost[i][0] = BIGV;
      #pragma unroll
      for (int j = 1; j <= 3; ++j) {
        cost[i][j] = D[i-1][j-1] +
            fminf(fminf(cost[i][j-1], cost[i-1][j-1]), cost[i-1][j]);
      }
    }

    // backtrace: start (3,3), acc = dots[2][2], 2K-1 = 5 steps
    float acc2 = dots[2][2];
    {
      float acc = acc2;
      int st = (3 << 2) | 3;
      bool active = true;
      #pragma unroll 1
      for (int s = 0; s < 5; ++s) {
        if (!active) break;
        switch (st) {
          TRACE_CASE(1, 1)
          TRACE_CASE(1, 2)
          TRACE_CASE(1, 3)
          TRACE_CASE(2, 1)
          TRACE_CASE(2, 2)
          TRACE_CASE(2, 3)
          TRACE_CASE(3, 1)
          TRACE_CASE(3, 2)
          TRACE_CASE(3, 3)
          default: active = false; break;
        }
      }
      acc2 = acc;
    }

    if (p < P) out[((size_t)b * P + p) * 8 + f] = fmaxf(acc2 + BI[f], 0.f);
  }
}

extern "C" void kernel_launch(void* const* d_in, const int* in_sizes, int n_in,
                              void* d_out, int out_size, void* d_ws, size_t ws_size,
                              hipStream_t stream) {
  const float* x    = (const float*)d_in[0];
  const float* w    = (const float*)d_in[1];
  const float* bias = (const float*)d_in[2];
  float* out        = (float*)d_out;

  constexpr int B = 32;
  dim3 grid(33, B);  // 33 * 62 = 2046 positions, 1056 blocks
  dwa_cnn_kernel<<<grid, 128, 0, stream>>>(x, w, bias, out);
}